// Round 7
// baseline (298.167 us; speedup 1.0000x reference)
//
#include <hip/hip_runtime.h>
#include <hip/hip_bf16.h>
#include <stdint.h>

// Problem constants: B=2, N=2048, K=48, H=128, 3H=384, FF=512
#define MIDP 136    // transposed per-wave mid pitch (bf16): [32][136] = 8704 B
#define XP2 264     // k_edge x_tile pitch (bf16): 132 dwords (132%32=4)
#define MP 136      // k_edge mid pitch
#define FFP 520     // ffn mid pitch
#define EPIP 132

typedef __attribute__((ext_vector_type(8))) short bf16x8;
typedef __attribute__((ext_vector_type(4))) float f32x4;

__device__ __forceinline__ f32x4 mfma16(bf16x8 a, bf16x8 b, f32x4 c) {
  return __builtin_amdgcn_mfma_f32_16x16x32_bf16(a, b, c, 0, 0, 0);
}

__device__ __forceinline__ void lds_fence() {
  asm volatile("" ::: "memory");
}

__device__ __forceinline__ uint16_t f2b(float f) {
  union { __hip_bfloat16 h; uint16_t u; } v;
  v.h = __float2bfloat16(f);
  return v.u;
}
__device__ __forceinline__ uint32_t pk2f(float a, float b) {
  union { __hip_bfloat162 h; uint32_t u; } v;
  v.h = __float22bfloat162_rn(make_float2(a, b));
  return v.u;
}
__device__ __forceinline__ float gelu_f(float x) {
  float u = __builtin_fmaf(x * x, 0.044715f, 1.0f);
  float e = __builtin_amdgcn_exp2f(-2.302585093f * x * u);
  return x * __builtin_amdgcn_rcpf(1.0f + e);
}
__device__ __forceinline__ int div48(int e) {  // e < 196608
  return (int)((((unsigned)e >> 4) * 0xAAABu) >> 17);
}

// ---------------- prep: bf16 h_V + transposed bf16 weights ----------------
__global__ __launch_bounds__(256) void k_prep(
    const float* __restrict__ hV,
    const float* __restrict__ W1, const float* __restrict__ W2, const float* __restrict__ W3,
    const float* __restrict__ WdIn, const float* __restrict__ WdOut,
    const float* __restrict__ W11, const float* __restrict__ W12, const float* __restrict__ W13,
    uint16_t* __restrict__ hVb,
    uint16_t* __restrict__ W1t, uint16_t* __restrict__ W2t, uint16_t* __restrict__ W3t,
    uint16_t* __restrict__ WdInT, uint16_t* __restrict__ WdOutT,
    uint16_t* __restrict__ W11t, uint16_t* __restrict__ W12t, uint16_t* __restrict__ W13t) {
  int i = blockIdx.x * 256 + threadIdx.x;
  if (i < 524288) { hVb[i] = f2b(hV[i]); return; }
  int j = i - 524288;
  if (j < 49152) { int n = j / 384, k = j - n * 384; W1t[j] = f2b(W1[k * 128 + n]); return; }
  j -= 49152;
  if (j < 16384) { int n = j >> 7, k = j & 127; W2t[j] = f2b(W2[k * 128 + n]); return; }
  j -= 16384;
  if (j < 16384) { int n = j >> 7, k = j & 127; W3t[j] = f2b(W3[k * 128 + n]); return; }
  j -= 16384;
  if (j < 65536) { int n = j >> 7, k = j & 127; WdInT[j] = f2b(WdIn[k * 512 + n]); return; }
  j -= 65536;
  if (j < 65536) { int n = j >> 9, k = j & 511; WdOutT[j] = f2b(WdOut[k * 128 + n]); return; }
  j -= 65536;
  if (j < 49152) { int n = j / 384, k = j - n * 384; W11t[j] = f2b(W11[k * 128 + n]); return; }
  j -= 49152;
  if (j < 16384) { int n = j >> 7, k = j & 127; W12t[j] = f2b(W12[k * 128 + n]); return; }
  j -= 16384;
  if (j < 16384) { int n = j >> 7, k = j & 127; W13t[j] = f2b(W13[k * 128 + n]); return; }
}

// ------- k_vec: C[i][n] = sum_{k<128} Xb[i][k]*Wt[n][k] + bias[n] -------
__global__ __launch_bounds__(256) void k_vec(
    const uint16_t* __restrict__ Xb, const uint16_t* __restrict__ Wt,
    const float* __restrict__ bias, float* __restrict__ C) {
  const int tid = threadIdx.x;
  const int lane = tid & 63, w = tid >> 6, l15 = lane & 15, lg = lane >> 4;
  const int row0 = blockIdx.x * 64 + w * 16;
  f32x4 acc[8] = {};
#pragma unroll
  for (int ks = 0; ks < 4; ++ks) {
    bf16x8 a = *(const bf16x8*)(Xb + (row0 + l15) * 128 + ks * 32 + lg * 8);
#pragma unroll
    for (int j = 0; j < 8; ++j) {
      bf16x8 bb = *(const bf16x8*)(Wt + (j * 16 + l15) * 384 + ks * 32 + lg * 8);
      acc[j] = mfma16(a, bb, acc[j]);
    }
  }
#pragma unroll
  for (int j = 0; j < 8; ++j) {
    float bs = bias[j * 16 + l15];
#pragma unroll
    for (int r = 0; r < 4; ++r)
      C[(row0 + lg * 4 + r) * 128 + j * 16 + l15] = acc[j][r] + bs;
  }
}

// ===== transposed MLP macros (k_node only; Output-0-verified in r5 & r6) =====
#define T_LAYER1(WTBL, GSRC, ACC)                                                   \
  do {                                                                              \
    _Pragma("unroll") for (int ks = 0; ks < 8; ++ks) {                              \
      bf16x8 xb[2];                                                                 \
      if (ks < 4) {                                                                 \
        _Pragma("unroll") for (int nt = 0; nt < 2; ++nt) {                          \
          const float* p_ = hE + (size_t)e_[nt] * 128 + ks * 32 + lg * 8;           \
          float4 f0_ = *(const float4*)p_;                                          \
          float4 f1_ = *(const float4*)(p_ + 4);                                    \
          union { bf16x8 v; uint32_t u[4]; } a_;                                    \
          a_.u[0] = pk2f(f0_.x, f0_.y); a_.u[1] = pk2f(f0_.z, f0_.w);               \
          a_.u[2] = pk2f(f1_.x, f1_.y); a_.u[3] = pk2f(f1_.z, f1_.w);               \
          xb[nt] = a_.v;                                                            \
        }                                                                           \
      } else {                                                                      \
        _Pragma("unroll") for (int nt = 0; nt < 2; ++nt)                            \
          xb[nt] = *(const bf16x8*)((GSRC) + (size_t)nb_[nt] * 128 +                \
                                    (ks - 4) * 32 + lg * 8);                        \
      }                                                                             \
      _Pragma("unroll") for (int m = 0; m < 8; ++m) {                               \
        bf16x8 wa_ = *(const bf16x8*)((WTBL) + (m * 16 + l15) * 384 + 128 +         \
                                      ks * 32 + lg * 8);                            \
        ACC[m][0] = mfma16(wa_, xb[0], ACC[m][0]);                                  \
        ACC[m][1] = mfma16(wa_, xb[1], ACC[m][1]);                                  \
      }                                                                             \
    }                                                                               \
  } while (0)

#define T_GELU_TO_MID(ACC)                                                          \
  do {                                                                              \
    _Pragma("unroll") for (int m = 0; m < 8; ++m)                                   \
    _Pragma("unroll") for (int nt = 0; nt < 2; ++nt) {                              \
      uint32_t p0_ = pk2f(gelu_f(ACC[m][nt][0]), gelu_f(ACC[m][nt][1]));            \
      uint32_t p1_ = pk2f(gelu_f(ACC[m][nt][2]), gelu_f(ACC[m][nt][3]));            \
      uint32_t* q_ = (uint32_t*)(mid + (nt * 16 + l15) * MIDP + m * 16 + lg * 4);   \
      q_[0] = p0_; q_[1] = p1_;                                                     \
    }                                                                               \
  } while (0)

#define T_LAYER128(WTBL, ACC)                                                       \
  do {                                                                              \
    _Pragma("unroll") for (int ks = 0; ks < 4; ++ks) {                              \
      bf16x8 xb[2];                                                                 \
      _Pragma("unroll") for (int nt = 0; nt < 2; ++nt)                              \
        xb[nt] = *(const bf16x8*)(mid + (nt * 16 + l15) * MIDP + ks * 32 + lg * 8); \
      _Pragma("unroll") for (int m = 0; m < 8; ++m) {                               \
        bf16x8 wa_ = *(const bf16x8*)((WTBL) + (m * 16 + l15) * 128 +               \
                                      ks * 32 + lg * 8);                            \
        ACC[m][0] = mfma16(wa_, xb[0], ACC[m][0]);                                  \
        ACC[m][1] = mfma16(wa_, xb[1], ACC[m][1]);                                  \
      }                                                                             \
    }                                                                               \
  } while (0)

#define T_BIAS_INIT(ACC, BIAS)                                                      \
  do {                                                                              \
    _Pragma("unroll") for (int m = 0; m < 8; ++m) {                                 \
      f32x4 v_;                                                                     \
      _Pragma("unroll") for (int r = 0; r < 4; ++r)                                 \
        v_[r] = (BIAS)[m * 16 + lg * 4 + r];                                        \
      ACC[m][0] = v_; ACC[m][1] = v_;                                               \
    }                                                                               \
  } while (0)

// ---------------- K1: node message MLP + masked sum + LN1 (transposed) ----------------
__global__ __launch_bounds__(192, 3) void k_node(
    const float* __restrict__ hV, const float* __restrict__ hE,
    const int* __restrict__ eidx, const float* __restrict__ maskA,
    const float* __restrict__ b2, const float* __restrict__ b3,
    const float* __restrict__ g1, const float* __restrict__ be1,
    const uint16_t* __restrict__ hVb, const float* __restrict__ C1,
    const uint16_t* __restrict__ W1t, const uint16_t* __restrict__ W2t,
    const uint16_t* __restrict__ W3t,
    float* __restrict__ hV1, uint16_t* __restrict__ hV1b) {
  __shared__ __align__(16) unsigned char lds[29184];
  const int tid = threadIdx.x;
  const int lane = tid & 63;
  const int w = tid >> 6;
  const int l15 = lane & 15;
  const int lg = lane >> 4;
  uint16_t* mid = (uint16_t*)(lds + w * 8704);
  float* dhc = (float*)(lds + 26112);  // [6][128]

  const int base = blockIdx.x * 96 + w * 32;
  int e_[2], nb_[2];
#pragma unroll
  for (int nt = 0; nt < 2; ++nt) {
    e_[nt] = base + nt * 16 + l15;
    nb_[nt] = ((e_[nt] >= 98304) ? 2048 : 0) + eidx[e_[nt]];
  }

  f32x4 acc1[8][2];
#pragma unroll
  for (int nt = 0; nt < 2; ++nt) {
    const float* cp = C1 + (size_t)div48(e_[nt]) * 128 + lg * 4;
#pragma unroll
    for (int m = 0; m < 8; ++m) {
      f32x4 v;
#pragma unroll
      for (int r = 0; r < 4; ++r) v[r] = cp[m * 16 + r];
      acc1[m][nt] = v;
    }
  }
  T_LAYER1(W1t, hVb, acc1);
  T_GELU_TO_MID(acc1);
  lds_fence();

  f32x4 acc2[8][2];
  T_BIAS_INIT(acc2, b2);
  T_LAYER128(W2t, acc2);
  T_GELU_TO_MID(acc2);
  lds_fence();

  f32x4 acc3[8][2];
  T_BIAS_INIT(acc3, b3);
  T_LAYER128(W3t, acc3);
  lds_fence();

  float mk[2];
#pragma unroll
  for (int nt = 0; nt < 2; ++nt) mk[nt] = maskA[e_[nt]];
#pragma unroll
  for (int m = 0; m < 8; ++m)
#pragma unroll
    for (int nt = 0; nt < 2; ++nt)
#pragma unroll
      for (int r = 0; r < 4; ++r) {
        float v = acc3[m][nt][r] * mk[nt];
        v += __shfl_xor(v, 1); v += __shfl_xor(v, 2);
        v += __shfl_xor(v, 4); v += __shfl_xor(v, 8);
        if (l15 == 0) dhc[(w * 2 + nt) * 128 + m * 16 + lg * 4 + r] = v;
      }
  __syncthreads();

  if (w < 2) {
    int node = blockIdx.x * 2 + w;
    const float* d0 = dhc + (3 * w) * 128;
    float dhA = d0[lane] + d0[128 + lane] + d0[256 + lane];
    float dhB = d0[64 + lane] + d0[192 + lane] + d0[320 + lane];
    const float inv = 1.0f / 30.0f;
    float x0 = hV[node * 128 + lane] + dhA * inv;
    float x1 = hV[node * 128 + 64 + lane] + dhB * inv;
    float s = x0 + x1, q = x0 * x0 + x1 * x1;
#pragma unroll
    for (int off = 1; off < 64; off <<= 1) {
      s += __shfl_xor(s, off);
      q += __shfl_xor(q, off);
    }
    float mean = s * (1.0f / 128.0f);
    float var = q * (1.0f / 128.0f) - mean * mean;
    float rstd = rsqrtf(var + 1e-5f);
    float y0 = (x0 - mean) * rstd * g1[lane] + be1[lane];
    float y1 = (x1 - mean) * rstd * g1[64 + lane] + be1[64 + lane];
    hV1[node * 128 + lane] = y0;
    hV1[node * 128 + 64 + lane] = y1;
    hV1b[node * 128 + lane] = f2b(y0);
    hV1b[node * 128 + 64 + lane] = f2b(y1);
  }
}

// ---------------- K2: position-wise FFN + LN2 + mask_V ----------------
__global__ __launch_bounds__(256, 2) void k_ffn(
    const float* __restrict__ hV1, const uint16_t* __restrict__ hV1b,
    const float* __restrict__ maskV,
    const float* __restrict__ bdin, const float* __restrict__ bdout,
    const float* __restrict__ g2, const float* __restrict__ be2,
    const uint16_t* __restrict__ WdInT, const uint16_t* __restrict__ WdOutT,
    float* __restrict__ outV, uint16_t* __restrict__ hV2b) {
  __shared__ __align__(16) unsigned char lds[20992];
  uint16_t* xa = (uint16_t*)lds;             // [16][136]
  uint16_t* mf = (uint16_t*)(lds + 4352);    // [16][520]
  float* epi = (float*)(lds + 4352);         // [16][132] overlays mf (barrier-protected)

  const int tid = threadIdx.x;
  const int lane = tid & 63;
  const int w = tid >> 6;
  const int l15 = lane & 15;
  const int lg = lane >> 4;
  const int node0 = blockIdx.x * 16;

  {
    int row = tid >> 4, c = tid & 15;
    *(uint4*)(xa + row * 136 + (c << 3)) =
        *(const uint4*)(hV1b + (node0 + row) * 128 + (c << 3));
  }
  __syncthreads();

  f32x4 acc[8] = {};
  {
    const uint16_t* ar = xa + l15 * 136 + lg * 8;
#pragma unroll
    for (int ks = 0; ks < 4; ++ks) {
      bf16x8 a = *(const bf16x8*)(ar + ks * 32);
#pragma unroll
      for (int j = 0; j < 8; ++j) {
        bf16x8 bb = *(const bf16x8*)(WdInT + ((w * 8 + j) * 16 + l15) * 128 + ks * 32 + lg * 8);
        acc[j] = mfma16(a, bb, acc[j]);
      }
    }
  }
#pragma unroll
  for (int j = 0; j < 8; ++j) {
    int col = (w * 8 + j) * 16 + l15;
    float bs = bdin[col];
#pragma unroll
    for (int r = 0; r < 4; ++r) {
      int row = lg * 4 + r;
      mf[row * FFP + col] = f2b(gelu_f(acc[j][r] + bs));
    }
  }
  __syncthreads();

  f32x4 acc2[2] = {};
  {
    const uint16_t* mr = mf + l15 * FFP + lg * 8;
#pragma unroll 4
    for (int ks = 0; ks < 16; ++ks) {
      bf16x8 a = *(const bf16x8*)(mr + ks * 32);
#pragma unroll
      for (int t = 0; t < 2; ++t) {
        bf16x8 bb = *(const bf16x8*)(WdOutT + ((w * 2 + t) * 16 + l15) * 512 + ks * 32 + lg * 8);
        acc2[t] = mfma16(a, bb, acc2[t]);
      }
    }
  }
  __syncthreads();
#pragma unroll
  for (int t = 0; t < 2; ++t) {
    int col = (w * 2 + t) * 16 + l15;
    float bs = bdout[col];
#pragma unroll
    for (int r = 0; r < 4; ++r) {
      int row = lg * 4 + r;
      epi[row * EPIP + col] = acc2[t][r] + bs;
    }
  }
  __syncthreads();

#pragma unroll
  for (int rr = 0; rr < 4; ++rr) {
    int row = w * 4 + rr;
    int node = node0 + row;
    float x0 = epi[row * EPIP + lane] + hV1[node * 128 + lane];
    float x1 = epi[row * EPIP + 64 + lane] + hV1[node * 128 + 64 + lane];
    float s = x0 + x1, q = x0 * x0 + x1 * x1;
#pragma unroll
    for (int off = 1; off < 64; off <<= 1) {
      s += __shfl_xor(s, off);
      q += __shfl_xor(q, off);
    }
    float mean = s * (1.0f / 128.0f);
    float var = q * (1.0f / 128.0f) - mean * mean;
    float rstd = rsqrtf(var + 1e-5f);
    float mv = maskV[node];
    float y0 = mv * ((x0 - mean) * rstd * g2[lane] + be2[lane]);
    float y1 = mv * ((x1 - mean) * rstd * g2[64 + lane] + be2[64 + lane]);
    outV[node * 128 + lane] = y0;
    outV[node * 128 + 64 + lane] = y1;
    hV2b[node * 128 + lane] = f2b(y0);
    hV2b[node * 128 + 64 + lane] = f2b(y1);
  }
}

// ===== round-4-style macros for k_edge (block-staged, r4-verified) =====
#define BUILD_XT(GSRC)                                                              \
  do {                                                                              \
    for (int idx = tid; idx < 48 * 32; idx += 256) {                                \
      int k_ = idx >> 5;                                                            \
      int c_ = idx & 31;                                                            \
      uint4 v_;                                                                     \
      if (c_ < 16) {                                                                \
        const float* s_ = hE + (size_t)(bn * 48 + k_) * 128 + (c_ << 3);            \
        float4 f0_ = *(const float4*)s_;                                            \
        float4 f1_ = *(const float4*)(s_ + 4);                                      \
        v_ = make_uint4(pk2f(f0_.x, f0_.y), pk2f(f0_.z, f0_.w),                     \
                        pk2f(f1_.x, f1_.y), pk2f(f1_.z, f1_.w));                    \
      } else {                                                                      \
        v_ = *(const uint4*)((GSRC) + (size_t)nbr[k_] * 128 + ((c_ - 16) << 3));    \
      }                                                                             \
      *(uint4*)(xt + k_ * XP2 + (c_ << 3)) = v_;                                    \
    }                                                                               \
  } while (0)

#define LAYER256(WT, ACC)                                                           \
  do {                                                                              \
    const uint16_t* wr0_ = (WT) + (w * 32 + l15) * 384 + 128 + lg * 8;              \
    const uint16_t* wr1_ = wr0_ + 16 * 384;                                         \
    _Pragma("unroll 2") for (int ks = 0; ks < 8; ++ks) {                            \
      bf16x8 bA_ = *(const bf16x8*)(wr0_ + ks * 32);                                \
      bf16x8 bB_ = *(const bf16x8*)(wr1_ + ks * 32);                                \
      _Pragma("unroll") for (int m = 0; m < 3; ++m) {                               \
        bf16x8 a_ = *(const bf16x8*)(xt + (m * 16 + l15) * XP2 + ks * 32 + lg * 8); \
        ACC[m][0] = mfma16(a_, bA_, ACC[m][0]);                                     \
        ACC[m][1] = mfma16(a_, bB_, ACC[m][1]);                                     \
      }                                                                             \
    }                                                                               \
  } while (0)

#define LAYER128(WT, ASRC, ACC)                                                     \
  do {                                                                              \
    const uint16_t* wr0_ = (WT) + (w * 32 + l15) * 128 + lg * 8;                    \
    const uint16_t* wr1_ = wr0_ + 16 * 128;                                         \
    _Pragma("unroll") for (int ks = 0; ks < 4; ++ks) {                              \
      bf16x8 bA_ = *(const bf16x8*)(wr0_ + ks * 32);                                \
      bf16x8 bB_ = *(const bf16x8*)(wr1_ + ks * 32);                                \
      _Pragma("unroll") for (int m = 0; m < 3; ++m) {                               \
        bf16x8 a_ = *(const bf16x8*)((ASRC) + (m * 16 + l15) * MP + ks * 32 + lg * 8); \
        ACC[m][0] = mfma16(a_, bA_, ACC[m][0]);                                     \
        ACC[m][1] = mfma16(a_, bB_, ACC[m][1]);                                     \
      }                                                                              \
    }                                                                               \
  } while (0)

#define GSTORE(ACC, BIAS, DST)                                                      \
  do {                                                                              \
    float bA_ = (BIAS)[w * 32 + l15];                                               \
    float bB_ = (BIAS)[w * 32 + 16 + l15];                                          \
    _Pragma("unroll") for (int m = 0; m < 3; ++m)                                   \
    _Pragma("unroll") for (int r = 0; r < 4; ++r) {                                 \
      int row_ = m * 16 + lg * 4 + r;                                               \
      (DST)[row_ * MP + w * 32 + l15] = f2b(gelu_f(ACC[m][0][r] + bA_));            \
      (DST)[row_ * MP + w * 32 + 16 + l15] = f2b(gelu_f(ACC[m][1][r] + bB_));       \
    }                                                                               \
  } while (0)

// layer-1 variant: bias already folded into the C-init (C2 carries b11)
#define GSTORE0(ACC, DST)                                                           \
  do {                                                                              \
    _Pragma("unroll") for (int m = 0; m < 3; ++m)                                   \
    _Pragma("unroll") for (int r = 0; r < 4; ++r) {                                 \
      int row_ = m * 16 + lg * 4 + r;                                               \
      (DST)[row_ * MP + w * 32 + l15] = f2b(gelu_f(ACC[m][0][r]));                  \
      (DST)[row_ * MP + w * 32 + 16 + l15] = f2b(gelu_f(ACC[m][1][r]));             \
    }                                                                               \
  } while (0)

#define ACC_INIT(ACC, CV)                                                           \
  do {                                                                              \
    float c0_ = (CV)[bn * 128 + w * 32 + l15];                                      \
    float c1_ = (CV)[bn * 128 + w * 32 + 16 + l15];                                 \
    _Pragma("unroll") for (int m = 0; m < 3; ++m) {                                 \
      ACC[m][0] = (f32x4){c0_, c0_, c0_, c0_};                                      \
      ACC[m][1] = (f32x4){c1_, c1_, c1_, c1_};                                      \
    }                                                                               \
  } while (0)

// ---------------- K3: edge MLP + residual + LN3 (round-4 verified structure) ----------------
// LDS: xt @0 (25344) | midA overlays xt @0 (13056) | midB @13056 (13056) |
//      nbr @26112 (192) = 26304 B; partials overlay dead midA space post-L3
__global__ __launch_bounds__(256, 6) void k_edge(
    const float* __restrict__ hE, const int* __restrict__ eidx,
    const float* __restrict__ bias2, const float* __restrict__ bias3,
    const float* __restrict__ g3, const float* __restrict__ be3,
    const uint16_t* __restrict__ hV2b, const float* __restrict__ C2,
    const uint16_t* __restrict__ W1t, const uint16_t* __restrict__ W2t,
    const uint16_t* __restrict__ W3t,
    float* __restrict__ outE) {
  __shared__ __align__(16) unsigned char lds[26304];
  uint16_t* xt = (uint16_t*)lds;
  uint16_t* midA = (uint16_t*)lds;
  uint16_t* midB = (uint16_t*)(lds + 13056);
  int* nbr = (int*)(lds + 26112);
  float* part_s = (float*)lds;            // [48][4] overlays dead midA
  float* part_q = (float*)(lds + 768);    // [48][4]
  float* mstd = (float*)(lds + 1536);     // [48][2] (mean, rstd)

  const int tid = threadIdx.x;
  const int lane = tid & 63;
  const int w = tid >> 6;
  const int l15 = lane & 15;
  const int lg = lane >> 4;
  const int bn = blockIdx.x;
  const int b = bn >> 11;

  if (tid < 48) nbr[tid] = (b << 11) + eidx[bn * 48 + tid];
  __syncthreads();

  BUILD_XT(hV2b);
  __syncthreads();

  f32x4 acc1[3][2];
  ACC_INIT(acc1, C2);
  LAYER256(W1t, acc1);
  __syncthreads();               // all xt reads done; midA may overlay
  GSTORE0(acc1, midA);
  __syncthreads();

  f32x4 acc2[3][2] = {};
  LAYER128(W2t, midA, acc2);
  GSTORE(acc2, bias2, midB);
  __syncthreads();

  f32x4 acc3[3][2] = {};
  LAYER128(W3t, midB, acc3);

  const float bA = bias3[w * 32 + l15];
  const float bB = bias3[w * 32 + 16 + l15];

  // x = acc3 + bias + hE residual, cached in VGPRs for both LN passes
  float xs0[3][4], xs1[3][4];
#pragma unroll
  for (int m = 0; m < 3; ++m)
#pragma unroll
    for (int r = 0; r < 4; ++r) {
      int row = m * 16 + lg * 4 + r;
      size_t e = (size_t)bn * 48 + row;
      xs0[m][r] = acc3[m][0][r] + bA + hE[e * 128 + w * 32 + l15];
      xs1[m][r] = acc3[m][1][r] + bB + hE[e * 128 + w * 32 + 16 + l15];
      float s = xs0[m][r] + xs1[m][r];
      float q = xs0[m][r] * xs0[m][r] + xs1[m][r] * xs1[m][r];
      s += __shfl_xor(s, 1); q += __shfl_xor(q, 1);
      s += __shfl_xor(s, 2); q += __shfl_xor(q, 2);
      s += __shfl_xor(s, 4); q += __shfl_xor(q, 4);
      s += __shfl_xor(s, 8); q += __shfl_xor(q, 8);
      if (l15 == 0) { part_s[row * 4 + w] = s; part_q[row * 4 + w] = q; }
    }
  __syncthreads();

  if (tid < 48) {
    float s = part_s[tid * 4] + part_s[tid * 4 + 1] + part_s[tid * 4 + 2] + part_s[tid * 4 + 3];
    float q = part_q[tid * 4] + part_q[tid * 4 + 1] + part_q[tid * 4 + 2] + part_q[tid * 4 + 3];
    float mean = s * (1.0f / 128.0f);
    float var = q * (1.0f / 128.0f) - mean * mean;
    mstd[tid * 2] = mean;
    mstd[tid * 2 + 1] = rsqrtf(var + 1e-5f);
  }
  __syncthreads();

  const float gA = g3[w * 32 + l15], beA = be3[w * 32 + l15];
  const float gB = g3[w * 32 + 16 + l15], beB = be3[w * 32 + 16 + l15];
#pragma unroll
  for (int m = 0; m < 3; ++m)
#pragma unroll
    for (int r = 0; r < 4; ++r) {
      int row = m * 16 + lg * 4 + r;
      size_t e = (size_t)bn * 48 + row;
      float mean = mstd[row * 2];
      float rstd = mstd[row * 2 + 1];
      outE[e * 128 + w * 32 + l15] = (xs0[m][r] - mean) * rstd * gA + beA;
      outE[e * 128 + w * 32 + 16 + l15] = (xs1[m][r] - mean) * rstd * gB + beB;
    }
}

extern "C" void kernel_launch(void* const* d_in, const int* in_sizes, int n_in,
                              void* d_out, int out_size, void* d_ws, size_t ws_size,
                              hipStream_t stream) {
  const float* hV = (const float*)d_in[0];
  const float* hE = (const float*)d_in[1];
  const int* eidx = (const int*)d_in[2];
  const float* maskV = (const float*)d_in[3];
  const float* maskA = (const float*)d_in[4];
  const float* W1 = (const float*)d_in[5];   const float* b1 = (const float*)d_in[6];
  const float* W2 = (const float*)d_in[7];   const float* b2 = (const float*)d_in[8];
  const float* W3 = (const float*)d_in[9];   const float* b3 = (const float*)d_in[10];
  const float* WdIn = (const float*)d_in[11];  const float* bdin = (const float*)d_in[12];
  const float* WdOut = (const float*)d_in[13]; const float* bdout = (const float*)d_in[14];
  const float* W11 = (const float*)d_in[15]; const float* b11 = (const float*)d_in[16];
  const float* W12 = (const float*)d_in[17]; const float* b12 = (const float*)d_in[18];
  const float* W13 = (const float*)d_in[19]; const float* b13 = (const float*)d_in[20];
  const float* n1g = (const float*)d_in[21]; const float* n1b = (const float*)d_in[22];
  const float* n2g = (const float*)d_in[23]; const float* n2b = (const float*)d_in[24];
  const float* n3g = (const float*)d_in[25]; const float* n3b = (const float*)d_in[26];

  char* ws = (char*)d_ws;
  uint16_t* hVb    = (uint16_t*)(ws + 0);
  uint16_t* W1t    = (uint16_t*)(ws + 1048576);
  uint16_t* W2t    = (uint16_t*)(ws + 1146880);
  uint16_t* W3t    = (uint16_t*)(ws + 1179648);
  uint16_t* WdInT  = (uint16_t*)(ws + 1212416);
  uint16_t* WdOutT = (uint16_t*)(ws + 1343488);
  uint16_t* W11t   = (uint16_t*)(ws + 1474560);
  uint16_t* W12t   = (uint16_t*)(ws + 1572864);
  uint16_t* W13t   = (uint16_t*)(ws + 1605632);
  float*    hV1    = (float*)(ws + 1638400);
  uint16_t* hV1b   = (uint16_t*)(ws + 3735552);
  uint16_t* hV2b   = (uint16_t*)(ws + 4784128);
  float*    C1     = (float*)(ws + 5832704);
  float*    C2     = (float*)(ws + 7929856);

  float* outV = (float*)d_out;
  float* outE = (float*)d_out + 524288;

  k_prep<<<3200, 256, 0, stream>>>(hV, W1, W2, W3, WdIn, WdOut, W11, W12, W13,
                                   hVb, W1t, W2t, W3t, WdInT, WdOutT, W11t, W12t, W13t);
  k_vec<<<64, 256, 0, stream>>>(hVb, W1t, b1, C1);
  k_node<<<2048, 192, 0, stream>>>(hV, hE, eidx, maskA, b2, b3, n1g, n1b,
                                   hVb, C1, W1t, W2t, W3t, hV1, hV1b);
  k_ffn<<<256, 256, 0, stream>>>(hV1, hV1b, maskV, bdin, bdout, n2g, n2b,
                                 WdInT, WdOutT, outV, hV2b);
  k_vec<<<64, 256, 0, stream>>>(hV2b, W11t, b11, C2);
  k_edge<<<4096, 256, 0, stream>>>(hE, eidx, b12, b13, n3g, n3b,
                                   hV2b, C2, W11t, W12t, W13t, outE);
}

// Round 8
// 224.639 us; speedup vs baseline: 1.3273x; 1.3273x over previous
//
#include <hip/hip_runtime.h>
#include <hip/hip_bf16.h>
#include <stdint.h>

// Problem constants: B=2, N=2048, K=48, H=128, 3H=384, FF=512
#define XP2 264     // x_tile pitch (bf16): 132 dwords (132%32=4, 2-way conflict only)
#define MP 136      // mid pitch (bf16): 68 dwords (68%32=4)
#define FFP 520     // ffn mid pitch
#define EPIP 132

typedef __attribute__((ext_vector_type(8))) short bf16x8;
typedef __attribute__((ext_vector_type(4))) float f32x4;

__device__ __forceinline__ f32x4 mfma16(bf16x8 a, bf16x8 b, f32x4 c) {
  return __builtin_amdgcn_mfma_f32_16x16x32_bf16(a, b, c, 0, 0, 0);
}

__device__ __forceinline__ uint16_t f2b(float f) {
  union { __hip_bfloat16 h; uint16_t u; } v;
  v.h = __float2bfloat16(f);
  return v.u;
}
__device__ __forceinline__ uint32_t pk2f(float a, float b) {
  union { __hip_bfloat162 h; uint32_t u; } v;
  v.h = __float22bfloat162_rn(make_float2(a, b));
  return v.u;
}
__device__ __forceinline__ float gelu_f(float x) {
  float u = __builtin_fmaf(x * x, 0.044715f, 1.0f);
  float e = __builtin_amdgcn_exp2f(-2.302585093f * x * u);
  return x * __builtin_amdgcn_rcpf(1.0f + e);
}

// ---------------- prep: bf16 h_V + transposed bf16 weights ----------------
__global__ __launch_bounds__(256) void k_prep(
    const float* __restrict__ hV,
    const float* __restrict__ W1, const float* __restrict__ W2, const float* __restrict__ W3,
    const float* __restrict__ WdIn, const float* __restrict__ WdOut,
    const float* __restrict__ W11, const float* __restrict__ W12, const float* __restrict__ W13,
    uint16_t* __restrict__ hVb,
    uint16_t* __restrict__ W1t, uint16_t* __restrict__ W2t, uint16_t* __restrict__ W3t,
    uint16_t* __restrict__ WdInT, uint16_t* __restrict__ WdOutT,
    uint16_t* __restrict__ W11t, uint16_t* __restrict__ W12t, uint16_t* __restrict__ W13t) {
  int i = blockIdx.x * 256 + threadIdx.x;
  if (i < 524288) { hVb[i] = f2b(hV[i]); return; }
  int j = i - 524288;
  if (j < 49152) { int n = j / 384, k = j - n * 384; W1t[j] = f2b(W1[k * 128 + n]); return; }
  j -= 49152;
  if (j < 16384) { int n = j >> 7, k = j & 127; W2t[j] = f2b(W2[k * 128 + n]); return; }
  j -= 16384;
  if (j < 16384) { int n = j >> 7, k = j & 127; W3t[j] = f2b(W3[k * 128 + n]); return; }
  j -= 16384;
  if (j < 65536) { int n = j >> 7, k = j & 127; WdInT[j] = f2b(WdIn[k * 512 + n]); return; }
  j -= 65536;
  if (j < 65536) { int n = j >> 9, k = j & 511; WdOutT[j] = f2b(WdOut[k * 128 + n]); return; }
  j -= 65536;
  if (j < 49152) { int n = j / 384, k = j - n * 384; W11t[j] = f2b(W11[k * 128 + n]); return; }
  j -= 49152;
  if (j < 16384) { int n = j >> 7, k = j & 127; W12t[j] = f2b(W12[k * 128 + n]); return; }
  j -= 16384;
  if (j < 16384) { int n = j >> 7, k = j & 127; W13t[j] = f2b(W13[k * 128 + n]); return; }
}

// ------- k_vec: C[i][n] = sum_{k<128} Xb[i][k]*Wt[n][k] + bias[n] -------
__global__ __launch_bounds__(256) void k_vec(
    const uint16_t* __restrict__ Xb, const uint16_t* __restrict__ Wt,
    const float* __restrict__ bias, float* __restrict__ C) {
  const int tid = threadIdx.x;
  const int lane = tid & 63, w = tid >> 6, l15 = lane & 15, lg = lane >> 4;
  const int row0 = blockIdx.x * 64 + w * 16;
  f32x4 acc[8] = {};
#pragma unroll
  for (int ks = 0; ks < 4; ++ks) {
    bf16x8 a = *(const bf16x8*)(Xb + (row0 + l15) * 128 + ks * 32 + lg * 8);
#pragma unroll
    for (int j = 0; j < 8; ++j) {
      bf16x8 bb = *(const bf16x8*)(Wt + (j * 16 + l15) * 384 + ks * 32 + lg * 8);
      acc[j] = mfma16(a, bb, acc[j]);
    }
  }
#pragma unroll
  for (int j = 0; j < 8; ++j) {
    float bs = bias[j * 16 + l15];
#pragma unroll
    for (int r = 0; r < 4; ++r)
      C[(row0 + lg * 4 + r) * 128 + j * 16 + l15] = acc[j][r] + bs;
  }
}

// ===== block-staged MLP macros (r4/r7-verified math) =====
#define BUILD_XT(GSRC)                                                              \
  do {                                                                              \
    for (int idx = tid; idx < 48 * 32; idx += 256) {                                \
      int k_ = idx >> 5;                                                            \
      int c_ = idx & 31;                                                            \
      uint4 v_;                                                                     \
      if (c_ < 16) {                                                                \
        const float* s_ = hE + (size_t)(bn * 48 + k_) * 128 + (c_ << 3);            \
        float4 f0_ = *(const float4*)s_;                                            \
        float4 f1_ = *(const float4*)(s_ + 4);                                      \
        v_ = make_uint4(pk2f(f0_.x, f0_.y), pk2f(f0_.z, f0_.w),                     \
                        pk2f(f1_.x, f1_.y), pk2f(f1_.z, f1_.w));                    \
      } else {                                                                      \
        v_ = *(const uint4*)((GSRC) + (size_t)nbr[k_] * 128 + ((c_ - 16) << 3));    \
      }                                                                             \
      *(uint4*)(xt + k_ * XP2 + (c_ << 3)) = v_;                                    \
    }                                                                               \
  } while (0)

// preload layer-1 weights (k>=128 half, 16 fragments = 64 VGPR)
#define PRELOAD_W384(WT, WF)                                                        \
  do {                                                                              \
    const uint16_t* p0_ = (WT) + (w * 32 + l15) * 384 + 128 + lg * 8;               \
    const uint16_t* p1_ = p0_ + 16 * 384;                                           \
    _Pragma("unroll") for (int ks = 0; ks < 8; ++ks) {                              \
      WF[ks] = *(const bf16x8*)(p0_ + ks * 32);                                     \
      WF[8 + ks] = *(const bf16x8*)(p1_ + ks * 32);                                 \
    }                                                                               \
  } while (0)

// preload K=128 layer weights (8 fragments = 32 VGPR)
#define PRELOAD_W128(WT, WF)                                                        \
  do {                                                                              \
    const uint16_t* p0_ = (WT) + (w * 32 + l15) * 128 + lg * 8;                     \
    const uint16_t* p1_ = p0_ + 16 * 128;                                           \
    _Pragma("unroll") for (int ks = 0; ks < 4; ++ks) {                              \
      WF[ks] = *(const bf16x8*)(p0_ + ks * 32);                                     \
      WF[4 + ks] = *(const bf16x8*)(p1_ + ks * 32);                                 \
    }                                                                               \
  } while (0)

#define LAYER256R(WF, ACC)                                                          \
  do {                                                                              \
    _Pragma("unroll") for (int ks = 0; ks < 8; ++ks)                                \
    _Pragma("unroll") for (int m = 0; m < 3; ++m) {                                 \
      bf16x8 a_ = *(const bf16x8*)(xt + (m * 16 + l15) * XP2 + ks * 32 + lg * 8);   \
      ACC[m][0] = mfma16(a_, WF[ks], ACC[m][0]);                                    \
      ACC[m][1] = mfma16(a_, WF[8 + ks], ACC[m][1]);                                \
    }                                                                               \
  } while (0)

#define LAYER128R(WF, ASRC, ACC)                                                    \
  do {                                                                              \
    _Pragma("unroll") for (int ks = 0; ks < 4; ++ks)                                \
    _Pragma("unroll") for (int m = 0; m < 3; ++m) {                                 \
      bf16x8 a_ = *(const bf16x8*)((ASRC) + (m * 16 + l15) * MP + ks * 32 + lg * 8);\
      ACC[m][0] = mfma16(a_, WF[ks], ACC[m][0]);                                    \
      ACC[m][1] = mfma16(a_, WF[4 + ks], ACC[m][1]);                                \
    }                                                                               \
  } while (0)

#define GSTORE(ACC, BIAS, DST)                                                      \
  do {                                                                              \
    float bA_ = (BIAS)[w * 32 + l15];                                               \
    float bB_ = (BIAS)[w * 32 + 16 + l15];                                          \
    _Pragma("unroll") for (int m = 0; m < 3; ++m)                                   \
    _Pragma("unroll") for (int r = 0; r < 4; ++r) {                                 \
      int row_ = m * 16 + lg * 4 + r;                                               \
      (DST)[row_ * MP + w * 32 + l15] = f2b(gelu_f(ACC[m][0][r] + bA_));            \
      (DST)[row_ * MP + w * 32 + 16 + l15] = f2b(gelu_f(ACC[m][1][r] + bB_));       \
    }                                                                               \
  } while (0)

// layer-1 variant: bias already folded into the C-init
#define GSTORE0(ACC, DST)                                                           \
  do {                                                                              \
    _Pragma("unroll") for (int m = 0; m < 3; ++m)                                   \
    _Pragma("unroll") for (int r = 0; r < 4; ++r) {                                 \
      int row_ = m * 16 + lg * 4 + r;                                               \
      (DST)[row_ * MP + w * 32 + l15] = f2b(gelu_f(ACC[m][0][r]));                  \
      (DST)[row_ * MP + w * 32 + 16 + l15] = f2b(gelu_f(ACC[m][1][r]));             \
    }                                                                               \
  } while (0)

#define ACC_INIT(ACC, CV)                                                           \
  do {                                                                              \
    float c0_ = (CV)[bn * 128 + w * 32 + l15];                                      \
    float c1_ = (CV)[bn * 128 + w * 32 + 16 + l15];                                 \
    _Pragma("unroll") for (int m = 0; m < 3; ++m) {                                 \
      ACC[m][0] = (f32x4){c0_, c0_, c0_, c0_};                                      \
      ACC[m][1] = (f32x4){c1_, c1_, c1_, c1_};                                      \
    }                                                                               \
  } while (0)

// ---------------- K1: node message MLP + masked sum + LN1 ----------------
// LDS: xt [48][264] @0 (25344) | midA overlays xt @0 (13056) | midB @13056 (13056) |
//      nbr @26112 (192) | dh @26368 (512) = 26880 B
__global__ __launch_bounds__(256, 4) void k_node(
    const float* __restrict__ hV, const float* __restrict__ hE,
    const int* __restrict__ eidx, const float* __restrict__ maskA,
    const float* __restrict__ bias2, const float* __restrict__ bias3,
    const float* __restrict__ g1, const float* __restrict__ be1,
    const uint16_t* __restrict__ hVb, const float* __restrict__ C1,
    const uint16_t* __restrict__ W1t, const uint16_t* __restrict__ W2t,
    const uint16_t* __restrict__ W3t,
    float* __restrict__ hV1, uint16_t* __restrict__ hV1b) {
  __shared__ __align__(16) unsigned char lds[26880];
  uint16_t* xt = (uint16_t*)lds;
  uint16_t* midA = (uint16_t*)lds;             // overlays xt after layer-1 barrier
  uint16_t* midB = (uint16_t*)(lds + 13056);
  int* nbr = (int*)(lds + 26112);
  float* dh = (float*)(lds + 26368);

  const int tid = threadIdx.x;
  const int lane = tid & 63;
  const int w = tid >> 6;
  const int l15 = lane & 15;
  const int lg = lane >> 4;
  const int bn = blockIdx.x;      // b*2048 + n
  const int b = bn >> 11;

  bf16x8 w1f[16];
  PRELOAD_W384(W1t, w1f);          // in flight during staging

  if (tid < 48) nbr[tid] = (b << 11) + eidx[bn * 48 + tid];
  __syncthreads();

  BUILD_XT(hVb);
  __syncthreads();

  f32x4 acc1[3][2];
  ACC_INIT(acc1, C1);
  LAYER256R(w1f, acc1);
  bf16x8 w2f[8];
  PRELOAD_W128(W2t, w2f);          // in flight during gelu + barriers
  __syncthreads();                 // all xt reads done; midA may overlay
  GSTORE0(acc1, midA);
  __syncthreads();

  f32x4 acc2[3][2] = {};
  LAYER128R(w2f, midA, acc2);
  bf16x8 w3f[8];
  PRELOAD_W128(W3t, w3f);          // in flight during gelu + barrier
  GSTORE(acc2, bias2, midB);       // disjoint from midA
  __syncthreads();

  f32x4 acc3[3][2] = {};
  LAYER128R(w3f, midB, acc3);

  // masked column sums over the 48 edge rows
  {
    float bA = bias3[w * 32 + l15];
    float bB = bias3[w * 32 + 16 + l15];
    float s0 = 0.f, s1 = 0.f;
#pragma unroll
    for (int m = 0; m < 3; ++m)
#pragma unroll
      for (int r = 0; r < 4; ++r) {
        int row = m * 16 + lg * 4 + r;
        float mk = maskA[bn * 48 + row];
        s0 += (acc3[m][0][r] + bA) * mk;
        s1 += (acc3[m][1][r] + bB) * mk;
      }
    s0 += __shfl_xor(s0, 16); s0 += __shfl_xor(s0, 32);
    s1 += __shfl_xor(s1, 16); s1 += __shfl_xor(s1, 32);
    if (lg == 0) { dh[w * 32 + l15] = s0; dh[w * 32 + 16 + l15] = s1; }
  }
  __syncthreads();

  if (w == 0) {
    const float inv = 1.0f / 30.0f;
    float x0 = hV[bn * 128 + lane] + dh[lane] * inv;
    float x1 = hV[bn * 128 + 64 + lane] + dh[64 + lane] * inv;
    float s = x0 + x1, q = x0 * x0 + x1 * x1;
#pragma unroll
    for (int off = 1; off < 64; off <<= 1) {
      s += __shfl_xor(s, off);
      q += __shfl_xor(q, off);
    }
    float mean = s * (1.0f / 128.0f);
    float var = q * (1.0f / 128.0f) - mean * mean;
    float rstd = rsqrtf(var + 1e-5f);
    float y0 = (x0 - mean) * rstd * g1[lane] + be1[lane];
    float y1 = (x1 - mean) * rstd * g1[64 + lane] + be1[64 + lane];
    hV1[bn * 128 + lane] = y0;
    hV1[bn * 128 + 64 + lane] = y1;
    hV1b[bn * 128 + lane] = f2b(y0);
    hV1b[bn * 128 + 64 + lane] = f2b(y1);
  }
}

// ---------------- K2: position-wise FFN + LN2 + mask_V ----------------
__global__ __launch_bounds__(256, 2) void k_ffn(
    const float* __restrict__ hV1, const uint16_t* __restrict__ hV1b,
    const float* __restrict__ maskV,
    const float* __restrict__ bdin, const float* __restrict__ bdout,
    const float* __restrict__ g2, const float* __restrict__ be2,
    const uint16_t* __restrict__ WdInT, const uint16_t* __restrict__ WdOutT,
    float* __restrict__ outV, uint16_t* __restrict__ hV2b) {
  __shared__ __align__(16) unsigned char lds[20992];
  uint16_t* xa = (uint16_t*)lds;             // [16][136]
  uint16_t* mf = (uint16_t*)(lds + 4352);    // [16][520]
  float* epi = (float*)(lds + 4352);         // [16][132] overlays mf (barrier-protected)

  const int tid = threadIdx.x;
  const int lane = tid & 63;
  const int w = tid >> 6;
  const int l15 = lane & 15;
  const int lg = lane >> 4;
  const int node0 = blockIdx.x * 16;

  {
    int row = tid >> 4, c = tid & 15;
    *(uint4*)(xa + row * 136 + (c << 3)) =
        *(const uint4*)(hV1b + (node0 + row) * 128 + (c << 3));
  }
  __syncthreads();

  f32x4 acc[8] = {};
  {
    const uint16_t* ar = xa + l15 * 136 + lg * 8;
#pragma unroll
    for (int ks = 0; ks < 4; ++ks) {
      bf16x8 a = *(const bf16x8*)(ar + ks * 32);
#pragma unroll
      for (int j = 0; j < 8; ++j) {
        bf16x8 bb = *(const bf16x8*)(WdInT + ((w * 8 + j) * 16 + l15) * 128 + ks * 32 + lg * 8);
        acc[j] = mfma16(a, bb, acc[j]);
      }
    }
  }
#pragma unroll
  for (int j = 0; j < 8; ++j) {
    int col = (w * 8 + j) * 16 + l15;
    float bs = bdin[col];
#pragma unroll
    for (int r = 0; r < 4; ++r) {
      int row = lg * 4 + r;
      mf[row * FFP + col] = f2b(gelu_f(acc[j][r] + bs));
    }
  }
  __syncthreads();

  f32x4 acc2[2] = {};
  {
    const uint16_t* mr = mf + l15 * FFP + lg * 8;
#pragma unroll 4
    for (int ks = 0; ks < 16; ++ks) {
      bf16x8 a = *(const bf16x8*)(mr + ks * 32);
#pragma unroll
      for (int t = 0; t < 2; ++t) {
        bf16x8 bb = *(const bf16x8*)(WdOutT + ((w * 2 + t) * 16 + l15) * 512 + ks * 32 + lg * 8);
        acc2[t] = mfma16(a, bb, acc2[t]);
      }
    }
  }
  __syncthreads();
#pragma unroll
  for (int t = 0; t < 2; ++t) {
    int col = (w * 2 + t) * 16 + l15;
    float bs = bdout[col];
#pragma unroll
    for (int r = 0; r < 4; ++r) {
      int row = lg * 4 + r;
      epi[row * EPIP + col] = acc2[t][r] + bs;
    }
  }
  __syncthreads();

#pragma unroll
  for (int rr = 0; rr < 4; ++rr) {
    int row = w * 4 + rr;
    int node = node0 + row;
    float x0 = epi[row * EPIP + lane] + hV1[node * 128 + lane];
    float x1 = epi[row * EPIP + 64 + lane] + hV1[node * 128 + 64 + lane];
    float s = x0 + x1, q = x0 * x0 + x1 * x1;
#pragma unroll
    for (int off = 1; off < 64; off <<= 1) {
      s += __shfl_xor(s, off);
      q += __shfl_xor(q, off);
    }
    float mean = s * (1.0f / 128.0f);
    float var = q * (1.0f / 128.0f) - mean * mean;
    float rstd = rsqrtf(var + 1e-5f);
    float mv = maskV[node];
    float y0 = mv * ((x0 - mean) * rstd * g2[lane] + be2[lane]);
    float y1 = mv * ((x1 - mean) * rstd * g2[64 + lane] + be2[64 + lane]);
    outV[node * 128 + lane] = y0;
    outV[node * 128 + 64 + lane] = y1;
    hV2b[node * 128 + lane] = f2b(y0);
    hV2b[node * 128 + 64 + lane] = f2b(y1);
  }
}

// ---------------- K3: edge MLP + residual + LN3 ----------------
// LDS: xt @0 (25344) | midA overlays xt @0 (13056) | midB @13056 (13056) |
//      nbr @26112 (192) = 26304 B; partials overlay dead midA space post-L3
__global__ __launch_bounds__(256, 4) void k_edge(
    const float* __restrict__ hE, const int* __restrict__ eidx,
    const float* __restrict__ bias2, const float* __restrict__ bias3,
    const float* __restrict__ g3, const float* __restrict__ be3,
    const uint16_t* __restrict__ hV2b, const float* __restrict__ C2,
    const uint16_t* __restrict__ W1t, const uint16_t* __restrict__ W2t,
    const uint16_t* __restrict__ W3t,
    float* __restrict__ outE) {
  __shared__ __align__(16) unsigned char lds[26304];
  uint16_t* xt = (uint16_t*)lds;
  uint16_t* midA = (uint16_t*)lds;
  uint16_t* midB = (uint16_t*)(lds + 13056);
  int* nbr = (int*)(lds + 26112);
  float* part_s = (float*)lds;            // [48][4] overlays dead midA
  float* part_q = (float*)(lds + 768);    // [48][4]
  float* mstd = (float*)(lds + 1536);     // [48][2] (mean, rstd)

  const int tid = threadIdx.x;
  const int lane = tid & 63;
  const int w = tid >> 6;
  const int l15 = lane & 15;
  const int lg = lane >> 4;
  const int bn = blockIdx.x;
  const int b = bn >> 11;

  bf16x8 w1f[16];
  PRELOAD_W384(W1t, w1f);

  if (tid < 48) nbr[tid] = (b << 11) + eidx[bn * 48 + tid];
  __syncthreads();

  BUILD_XT(hV2b);
  __syncthreads();

  f32x4 acc1[3][2];
  ACC_INIT(acc1, C2);
  LAYER256R(w1f, acc1);
  bf16x8 w2f[8];
  PRELOAD_W128(W2t, w2f);
  __syncthreads();               // all xt reads done; midA may overlay
  GSTORE0(acc1, midA);
  __syncthreads();

  f32x4 acc2[3][2] = {};
  LAYER128R(w2f, midA, acc2);
  bf16x8 w3f[8];
  PRELOAD_W128(W3t, w3f);
  GSTORE(acc2, bias2, midB);
  __syncthreads();

  f32x4 acc3[3][2] = {};
  LAYER128R(w3f, midB, acc3);

  const float bA = bias3[w * 32 + l15];
  const float bB = bias3[w * 32 + 16 + l15];

  // x = acc3 + bias + hE residual, cached in VGPRs for both LN passes
  float xs0[3][4], xs1[3][4];
#pragma unroll
  for (int m = 0; m < 3; ++m)
#pragma unroll
    for (int r = 0; r < 4; ++r) {
      int row = m * 16 + lg * 4 + r;
      size_t e = (size_t)bn * 48 + row;
      xs0[m][r] = acc3[m][0][r] + bA + hE[e * 128 + w * 32 + l15];
      xs1[m][r] = acc3[m][1][r] + bB + hE[e * 128 + w * 32 + 16 + l15];
      float s = xs0[m][r] + xs1[m][r];
      float q = xs0[m][r] * xs0[m][r] + xs1[m][r] * xs1[m][r];
      s += __shfl_xor(s, 1); q += __shfl_xor(q, 1);
      s += __shfl_xor(s, 2); q += __shfl_xor(q, 2);
      s += __shfl_xor(s, 4); q += __shfl_xor(q, 4);
      s += __shfl_xor(s, 8); q += __shfl_xor(q, 8);
      if (l15 == 0) { part_s[row * 4 + w] = s; part_q[row * 4 + w] = q; }
    }
  __syncthreads();

  if (tid < 48) {
    float s = part_s[tid * 4] + part_s[tid * 4 + 1] + part_s[tid * 4 + 2] + part_s[tid * 4 + 3];
    float q = part_q[tid * 4] + part_q[tid * 4 + 1] + part_q[tid * 4 + 2] + part_q[tid * 4 + 3];
    float mean = s * (1.0f / 128.0f);
    float var = q * (1.0f / 128.0f) - mean * mean;
    mstd[tid * 2] = mean;
    mstd[tid * 2 + 1] = rsqrtf(var + 1e-5f);
  }
  __syncthreads();

  const float gA = g3[w * 32 + l15], beA = be3[w * 32 + l15];
  const float gB = g3[w * 32 + 16 + l15], beB = be3[w * 32 + 16 + l15];
#pragma unroll
  for (int m = 0; m < 3; ++m)
#pragma unroll
    for (int r = 0; r < 4; ++r) {
      int row = m * 16 + lg * 4 + r;
      size_t e = (size_t)bn * 48 + row;
      float mean = mstd[row * 2];
      float rstd = mstd[row * 2 + 1];
      outE[e * 128 + w * 32 + l15] = (xs0[m][r] - mean) * rstd * gA + beA;
      outE[e * 128 + w * 32 + 16 + l15] = (xs1[m][r] - mean) * rstd * gB + beB;
    }
}

extern "C" void kernel_launch(void* const* d_in, const int* in_sizes, int n_in,
                              void* d_out, int out_size, void* d_ws, size_t ws_size,
                              hipStream_t stream) {
  const float* hV = (const float*)d_in[0];
  const float* hE = (const float*)d_in[1];
  const int* eidx = (const int*)d_in[2];
  const float* maskV = (const float*)d_in[3];
  const float* maskA = (const float*)d_in[4];
  const float* W1 = (const float*)d_in[5];   const float* b1 = (const float*)d_in[6];
  const float* W2 = (const float*)d_in[7];   const float* b2 = (const float*)d_in[8];
  const float* W3 = (const float*)d_in[9];   const float* b3 = (const float*)d_in[10];
  const float* WdIn = (const float*)d_in[11];  const float* bdin = (const float*)d_in[12];
  const float* WdOut = (const float*)d_in[13]; const float* bdout = (const float*)d_in[14];
  const float* W11 = (const float*)d_in[15]; const float* b11 = (const float*)d_in[16];
  const float* W12 = (const float*)d_in[17]; const float* b12 = (const float*)d_in[18];
  const float* W13 = (const float*)d_in[19]; const float* b13 = (const float*)d_in[20];
  const float* n1g = (const float*)d_in[21]; const float* n1b = (const float*)d_in[22];
  const float* n2g = (const float*)d_in[23]; const float* n2b = (const float*)d_in[24];
  const float* n3g = (const float*)d_in[25]; const float* n3b = (const float*)d_in[26];

  char* ws = (char*)d_ws;
  uint16_t* hVb    = (uint16_t*)(ws + 0);
  uint16_t* W1t    = (uint16_t*)(ws + 1048576);
  uint16_t* W2t    = (uint16_t*)(ws + 1146880);
  uint16_t* W3t    = (uint16_t*)(ws + 1179648);
  uint16_t* WdInT  = (uint16_t*)(ws + 1212416);
  uint16_t* WdOutT = (uint16_t*)(ws + 1343488);
  uint16_t* W11t   = (uint16_t*)(ws + 1474560);
  uint16_t* W12t   = (uint16_t*)(ws + 1572864);
  uint16_t* W13t   = (uint16_t*)(ws + 1605632);
  float*    hV1    = (float*)(ws + 1638400);
  uint16_t* hV1b   = (uint16_t*)(ws + 3735552);
  uint16_t* hV2b   = (uint16_t*)(ws + 4784128);
  float*    C1     = (float*)(ws + 5832704);
  float*    C2     = (float*)(ws + 7929856);

  float* outV = (float*)d_out;
  float* outE = (float*)d_out + 524288;

  k_prep<<<3200, 256, 0, stream>>>(hV, W1, W2, W3, WdIn, WdOut, W11, W12, W13,
                                   hVb, W1t, W2t, W3t, WdInT, WdOutT, W11t, W12t, W13t);
  k_vec<<<64, 256, 0, stream>>>(hVb, W1t, b1, C1);
  k_node<<<4096, 256, 0, stream>>>(hV, hE, eidx, maskA, b2, b3, n1g, n1b,
                                   hVb, C1, W1t, W2t, W3t, hV1, hV1b);
  k_ffn<<<256, 256, 0, stream>>>(hV1, hV1b, maskV, bdin, bdout, n2g, n2b,
                                 WdInT, WdOutT, outV, hV2b);
  k_vec<<<64, 256, 0, stream>>>(hV2b, W11t, b11, C2);
  k_edge<<<4096, 256, 0, stream>>>(hE, eidx, b12, b13, n3g, n3b,
                                   hV2b, C2, W11t, W12t, W13t, outE);
}

// Round 9
// 222.139 us; speedup vs baseline: 1.3423x; 1.0113x over previous
//
#include <hip/hip_runtime.h>
#include <hip/hip_bf16.h>
#include <stdint.h>

// Problem constants: B=2, N=2048, K=48, H=128, 3H=384, FF=512
// 2 nodes per block: 96 edge rows, 4 waves, wave w owns out-cols w*32..w*32+31.
#define XP2 264     // x_tile pitch (bf16): 132 dwords (132%32=4 -> 2-way, free)
#define MP 136      // mid pitch (bf16): 68 dwords (68%32=4)
#define FFP 520     // ffn mid pitch
#define EPIP 132

typedef __attribute__((ext_vector_type(8))) short bf16x8;
typedef __attribute__((ext_vector_type(4))) float f32x4;

__device__ __forceinline__ f32x4 mfma16(bf16x8 a, bf16x8 b, f32x4 c) {
  return __builtin_amdgcn_mfma_f32_16x16x32_bf16(a, b, c, 0, 0, 0);
}

__device__ __forceinline__ uint16_t f2b(float f) {
  union { __hip_bfloat16 h; uint16_t u; } v;
  v.h = __float2bfloat16(f);
  return v.u;
}
__device__ __forceinline__ uint32_t pk2f(float a, float b) {
  union { __hip_bfloat162 h; uint32_t u; } v;
  v.h = __float22bfloat162_rn(make_float2(a, b));
  return v.u;
}
__device__ __forceinline__ float gelu_f(float x) {
  float u = __builtin_fmaf(x * x, 0.044715f, 1.0f);
  float e = __builtin_amdgcn_exp2f(-2.302585093f * x * u);
  return x * __builtin_amdgcn_rcpf(1.0f + e);
}

// ---------------- prep: bf16 h_V + transposed bf16 weights ----------------
__global__ __launch_bounds__(256) void k_prep(
    const float* __restrict__ hV,
    const float* __restrict__ W1, const float* __restrict__ W2, const float* __restrict__ W3,
    const float* __restrict__ WdIn, const float* __restrict__ WdOut,
    const float* __restrict__ W11, const float* __restrict__ W12, const float* __restrict__ W13,
    uint16_t* __restrict__ hVb,
    uint16_t* __restrict__ W1t, uint16_t* __restrict__ W2t, uint16_t* __restrict__ W3t,
    uint16_t* __restrict__ WdInT, uint16_t* __restrict__ WdOutT,
    uint16_t* __restrict__ W11t, uint16_t* __restrict__ W12t, uint16_t* __restrict__ W13t) {
  int i = blockIdx.x * 256 + threadIdx.x;
  if (i < 524288) { hVb[i] = f2b(hV[i]); return; }
  int j = i - 524288;
  if (j < 49152) { int n = j / 384, k = j - n * 384; W1t[j] = f2b(W1[k * 128 + n]); return; }
  j -= 49152;
  if (j < 16384) { int n = j >> 7, k = j & 127; W2t[j] = f2b(W2[k * 128 + n]); return; }
  j -= 16384;
  if (j < 16384) { int n = j >> 7, k = j & 127; W3t[j] = f2b(W3[k * 128 + n]); return; }
  j -= 16384;
  if (j < 65536) { int n = j >> 7, k = j & 127; WdInT[j] = f2b(WdIn[k * 512 + n]); return; }
  j -= 65536;
  if (j < 65536) { int n = j >> 9, k = j & 511; WdOutT[j] = f2b(WdOut[k * 128 + n]); return; }
  j -= 65536;
  if (j < 49152) { int n = j / 384, k = j - n * 384; W11t[j] = f2b(W11[k * 128 + n]); return; }
  j -= 49152;
  if (j < 16384) { int n = j >> 7, k = j & 127; W12t[j] = f2b(W12[k * 128 + n]); return; }
  j -= 16384;
  if (j < 16384) { int n = j >> 7, k = j & 127; W13t[j] = f2b(W13[k * 128 + n]); return; }
}

// ------- k_vec: C[i][n] = sum_{k<128} Xb[i][k]*Wt[n][k] + bias[n] -------
__global__ __launch_bounds__(256) void k_vec(
    const uint16_t* __restrict__ Xb, const uint16_t* __restrict__ Wt,
    const float* __restrict__ bias, float* __restrict__ C) {
  const int tid = threadIdx.x;
  const int lane = tid & 63, w = tid >> 6, l15 = lane & 15, lg = lane >> 4;
  const int row0 = blockIdx.x * 64 + w * 16;
  f32x4 acc[8] = {};
#pragma unroll
  for (int ks = 0; ks < 4; ++ks) {
    bf16x8 a = *(const bf16x8*)(Xb + (row0 + l15) * 128 + ks * 32 + lg * 8);
#pragma unroll
    for (int j = 0; j < 8; ++j) {
      bf16x8 bb = *(const bf16x8*)(Wt + (j * 16 + l15) * 384 + ks * 32 + lg * 8);
      acc[j] = mfma16(a, bb, acc[j]);
    }
  }
#pragma unroll
  for (int j = 0; j < 8; ++j) {
    float bs = bias[j * 16 + l15];
#pragma unroll
    for (int r = 0; r < 4; ++r)
      C[(row0 + lg * 4 + r) * 128 + j * 16 + l15] = acc[j][r] + bs;
  }
}

// ===== 96-row block-staged MLP macros =====
// base = blockIdx*96 (edges are contiguous across the 2 nodes)
#define BUILD_XT96(GSRC)                                                            \
  do {                                                                              \
    for (int idx = tid; idx < 96 * 32; idx += 256) {                                \
      int k_ = idx >> 5;                                                            \
      int c_ = idx & 31;                                                            \
      uint4 v_;                                                                     \
      if (c_ < 16) {                                                                \
        const float* s_ = hE + (size_t)(base + k_) * 128 + (c_ << 3);               \
        float4 f0_ = *(const float4*)s_;                                            \
        float4 f1_ = *(const float4*)(s_ + 4);                                      \
        v_ = make_uint4(pk2f(f0_.x, f0_.y), pk2f(f0_.z, f0_.w),                     \
                        pk2f(f1_.x, f1_.y), pk2f(f1_.z, f1_.w));                    \
      } else {                                                                      \
        v_ = *(const uint4*)((GSRC) + (size_t)nbr[k_] * 128 + ((c_ - 16) << 3));    \
      }                                                                             \
      *(uint4*)(xt + k_ * XP2 + (c_ << 3)) = v_;                                    \
    }                                                                               \
  } while (0)

// preload layer-1 weights (k>=128 half, 16 fragments = 64 VGPR)
#define PRELOAD_W384(WT, WF)                                                        \
  do {                                                                              \
    const uint16_t* p0_ = (WT) + (w * 32 + l15) * 384 + 128 + lg * 8;               \
    const uint16_t* p1_ = p0_ + 16 * 384;                                           \
    _Pragma("unroll") for (int ks = 0; ks < 8; ++ks) {                              \
      WF[ks] = *(const bf16x8*)(p0_ + ks * 32);                                     \
      WF[8 + ks] = *(const bf16x8*)(p1_ + ks * 32);                                 \
    }                                                                               \
  } while (0)

#define PRELOAD_W128(WT, WF)                                                        \
  do {                                                                              \
    const uint16_t* p0_ = (WT) + (w * 32 + l15) * 128 + lg * 8;                     \
    const uint16_t* p1_ = p0_ + 16 * 128;                                           \
    _Pragma("unroll") for (int ks = 0; ks < 4; ++ks) {                              \
      WF[ks] = *(const bf16x8*)(p0_ + ks * 32);                                     \
      WF[4 + ks] = *(const bf16x8*)(p1_ + ks * 32);                                 \
    }                                                                               \
  } while (0)

#define LAYER256R6(WF, ACC)                                                         \
  do {                                                                              \
    _Pragma("unroll") for (int ks = 0; ks < 8; ++ks)                                \
    _Pragma("unroll") for (int m = 0; m < 6; ++m) {                                 \
      bf16x8 a_ = *(const bf16x8*)(xt + (m * 16 + l15) * XP2 + ks * 32 + lg * 8);   \
      ACC[m][0] = mfma16(a_, WF[ks], ACC[m][0]);                                    \
      ACC[m][1] = mfma16(a_, WF[8 + ks], ACC[m][1]);                                \
    }                                                                               \
  } while (0)

#define LAYER128R6(WF, ASRC, ACC)                                                   \
  do {                                                                              \
    _Pragma("unroll") for (int ks = 0; ks < 4; ++ks)                                \
    _Pragma("unroll") for (int m = 0; m < 6; ++m) {                                 \
      bf16x8 a_ = *(const bf16x8*)((ASRC) + (m * 16 + l15) * MP + ks * 32 + lg * 8);\
      ACC[m][0] = mfma16(a_, WF[ks], ACC[m][0]);                                    \
      ACC[m][1] = mfma16(a_, WF[4 + ks], ACC[m][1]);                                \
    }                                                                               \
  } while (0)

#define GSTORE6(ACC, BIAS, DST)                                                     \
  do {                                                                              \
    float bA_ = (BIAS)[w * 32 + l15];                                               \
    float bB_ = (BIAS)[w * 32 + 16 + l15];                                          \
    _Pragma("unroll") for (int m = 0; m < 6; ++m)                                   \
    _Pragma("unroll") for (int r = 0; r < 4; ++r) {                                 \
      int row_ = m * 16 + lg * 4 + r;                                               \
      (DST)[row_ * MP + w * 32 + l15] = f2b(gelu_f(ACC[m][0][r] + bA_));            \
      (DST)[row_ * MP + w * 32 + 16 + l15] = f2b(gelu_f(ACC[m][1][r] + bB_));       \
    }                                                                               \
  } while (0)

// layer-1 variant: bias already folded into the C-init
#define GSTORE06(ACC, DST)                                                          \
  do {                                                                              \
    _Pragma("unroll") for (int m = 0; m < 6; ++m)                                   \
    _Pragma("unroll") for (int r = 0; r < 4; ++r) {                                 \
      int row_ = m * 16 + lg * 4 + r;                                               \
      (DST)[row_ * MP + w * 32 + l15] = f2b(gelu_f(ACC[m][0][r]));                  \
      (DST)[row_ * MP + w * 32 + 16 + l15] = f2b(gelu_f(ACC[m][1][r]));             \
    }                                                                               \
  } while (0)

// per-node C-init: rows m<3 = node nd0, m>=3 = node nd0+1 (bias folded into C)
#define ACC_INIT6(ACC, CV)                                                          \
  do {                                                                              \
    float c0a_ = (CV)[(size_t)nd0 * 128 + w * 32 + l15];                            \
    float c1a_ = (CV)[(size_t)nd0 * 128 + w * 32 + 16 + l15];                       \
    float c0b_ = (CV)[(size_t)(nd0 + 1) * 128 + w * 32 + l15];                      \
    float c1b_ = (CV)[(size_t)(nd0 + 1) * 128 + w * 32 + 16 + l15];                 \
    _Pragma("unroll") for (int m = 0; m < 6; ++m) {                                 \
      float a_ = (m < 3) ? c0a_ : c0b_;                                             \
      float b_ = (m < 3) ? c1a_ : c1b_;                                             \
      ACC[m][0] = (f32x4){a_, a_, a_, a_};                                          \
      ACC[m][1] = (f32x4){b_, b_, b_, b_};                                          \
    }                                                                               \
  } while (0)

// ---------------- K1: node message MLP + masked sum + LN1 (2 nodes/block) ----------------
// LDS: xt [96][264] @0 (50688) | midA overlays xt @0 (26112) | midB @26112 (26112) |
//      nbr @52224 (384) = 52608 B; dh [2][128] f32 overlays dead midA @0
__global__ __launch_bounds__(256, 3) void k_node(
    const float* __restrict__ hV, const float* __restrict__ hE,
    const int* __restrict__ eidx, const float* __restrict__ maskA,
    const float* __restrict__ bias2, const float* __restrict__ bias3,
    const float* __restrict__ g1, const float* __restrict__ be1,
    const uint16_t* __restrict__ hVb, const float* __restrict__ C1,
    const uint16_t* __restrict__ W1t, const uint16_t* __restrict__ W2t,
    const uint16_t* __restrict__ W3t,
    float* __restrict__ hV1, uint16_t* __restrict__ hV1b) {
  __shared__ __align__(16) unsigned char lds[52608];
  uint16_t* xt = (uint16_t*)lds;
  uint16_t* midA = (uint16_t*)lds;             // overlays xt after post-L1 barrier
  uint16_t* midB = (uint16_t*)(lds + 26112);
  int* nbr = (int*)(lds + 52224);
  float* dh = (float*)lds;                     // [2][128], overlays dead midA

  const int tid = threadIdx.x;
  const int lane = tid & 63;
  const int w = tid >> 6;
  const int l15 = lane & 15;
  const int lg = lane >> 4;
  const int nd0 = blockIdx.x * 2;
  const int base = blockIdx.x * 96;            // first edge row

  bf16x8 w1f[16];
  PRELOAD_W384(W1t, w1f);

  if (tid < 96) {
    int e = base + tid;
    nbr[tid] = ((e >= 98304) ? 2048 : 0) + eidx[e];
  }
  __syncthreads();

  BUILD_XT96(hVb);
  __syncthreads();

  f32x4 acc1[6][2];
  ACC_INIT6(acc1, C1);
  LAYER256R6(w1f, acc1);
  bf16x8 w2f[8];
  PRELOAD_W128(W2t, w2f);
  __syncthreads();               // all xt reads done; midA may overlay
  GSTORE06(acc1, midA);
  __syncthreads();

  f32x4 acc2[6][2] = {};
  LAYER128R6(w2f, midA, acc2);
  bf16x8 w3f[8];
  PRELOAD_W128(W3t, w3f);
  GSTORE6(acc2, bias2, midB);
  __syncthreads();               // midA reads done (dh overlay safe after this)

  f32x4 acc3[6][2] = {};
  LAYER128R6(w3f, midB, acc3);

  // masked column sums per node over its 48 rows
  {
    float bA = bias3[w * 32 + l15];
    float bB = bias3[w * 32 + 16 + l15];
    float s0a = 0.f, s1a = 0.f, s0b = 0.f, s1b = 0.f;
#pragma unroll
    for (int m = 0; m < 6; ++m)
#pragma unroll
      for (int r = 0; r < 4; ++r) {
        int row = m * 16 + lg * 4 + r;
        float mk = maskA[base + row];
        float v0 = (acc3[m][0][r] + bA) * mk;
        float v1 = (acc3[m][1][r] + bB) * mk;
        if (m < 3) { s0a += v0; s1a += v1; } else { s0b += v0; s1b += v1; }
      }
    s0a += __shfl_xor(s0a, 16); s0a += __shfl_xor(s0a, 32);
    s1a += __shfl_xor(s1a, 16); s1a += __shfl_xor(s1a, 32);
    s0b += __shfl_xor(s0b, 16); s0b += __shfl_xor(s0b, 32);
    s1b += __shfl_xor(s1b, 16); s1b += __shfl_xor(s1b, 32);
    if (lg == 0) {
      dh[w * 32 + l15] = s0a;        dh[w * 32 + 16 + l15] = s1a;
      dh[128 + w * 32 + l15] = s0b;  dh[128 + w * 32 + 16 + l15] = s1b;
    }
  }
  __syncthreads();

  if (w < 2) {
    int node = nd0 + w;
    const float inv = 1.0f / 30.0f;
    float x0 = hV[(size_t)node * 128 + lane] + dh[w * 128 + lane] * inv;
    float x1 = hV[(size_t)node * 128 + 64 + lane] + dh[w * 128 + 64 + lane] * inv;
    float s = x0 + x1, q = x0 * x0 + x1 * x1;
#pragma unroll
    for (int off = 1; off < 64; off <<= 1) {
      s += __shfl_xor(s, off);
      q += __shfl_xor(q, off);
    }
    float mean = s * (1.0f / 128.0f);
    float var = q * (1.0f / 128.0f) - mean * mean;
    float rstd = rsqrtf(var + 1e-5f);
    float y0 = (x0 - mean) * rstd * g1[lane] + be1[lane];
    float y1 = (x1 - mean) * rstd * g1[64 + lane] + be1[64 + lane];
    hV1[(size_t)node * 128 + lane] = y0;
    hV1[(size_t)node * 128 + 64 + lane] = y1;
    hV1b[(size_t)node * 128 + lane] = f2b(y0);
    hV1b[(size_t)node * 128 + 64 + lane] = f2b(y1);
  }
}

// ---------------- K2: position-wise FFN + LN2 + mask_V ----------------
__global__ __launch_bounds__(256, 2) void k_ffn(
    const float* __restrict__ hV1, const uint16_t* __restrict__ hV1b,
    const float* __restrict__ maskV,
    const float* __restrict__ bdin, const float* __restrict__ bdout,
    const float* __restrict__ g2, const float* __restrict__ be2,
    const uint16_t* __restrict__ WdInT, const uint16_t* __restrict__ WdOutT,
    float* __restrict__ outV, uint16_t* __restrict__ hV2b) {
  __shared__ __align__(16) unsigned char lds[20992];
  uint16_t* xa = (uint16_t*)lds;             // [16][136]
  uint16_t* mf = (uint16_t*)(lds + 4352);    // [16][520]
  float* epi = (float*)(lds + 4352);         // [16][132] overlays mf (barrier-protected)

  const int tid = threadIdx.x;
  const int lane = tid & 63;
  const int w = tid >> 6;
  const int l15 = lane & 15;
  const int lg = lane >> 4;
  const int node0 = blockIdx.x * 16;

  {
    int row = tid >> 4, c = tid & 15;
    *(uint4*)(xa + row * 136 + (c << 3)) =
        *(const uint4*)(hV1b + (node0 + row) * 128 + (c << 3));
  }
  __syncthreads();

  f32x4 acc[8] = {};
  {
    const uint16_t* ar = xa + l15 * 136 + lg * 8;
#pragma unroll
    for (int ks = 0; ks < 4; ++ks) {
      bf16x8 a = *(const bf16x8*)(ar + ks * 32);
#pragma unroll
      for (int j = 0; j < 8; ++j) {
        bf16x8 bb = *(const bf16x8*)(WdInT + ((w * 8 + j) * 16 + l15) * 128 + ks * 32 + lg * 8);
        acc[j] = mfma16(a, bb, acc[j]);
      }
    }
  }
#pragma unroll
  for (int j = 0; j < 8; ++j) {
    int col = (w * 8 + j) * 16 + l15;
    float bs = bdin[col];
#pragma unroll
    for (int r = 0; r < 4; ++r) {
      int row = lg * 4 + r;
      mf[row * FFP + col] = f2b(gelu_f(acc[j][r] + bs));
    }
  }
  __syncthreads();

  f32x4 acc2[2] = {};
  {
    const uint16_t* mr = mf + l15 * FFP + lg * 8;
#pragma unroll 4
    for (int ks = 0; ks < 16; ++ks) {
      bf16x8 a = *(const bf16x8*)(mr + ks * 32);
#pragma unroll
      for (int t = 0; t < 2; ++t) {
        bf16x8 bb = *(const bf16x8*)(WdOutT + ((w * 2 + t) * 16 + l15) * 512 + ks * 32 + lg * 8);
        acc2[t] = mfma16(a, bb, acc2[t]);
      }
    }
  }
  __syncthreads();
#pragma unroll
  for (int t = 0; t < 2; ++t) {
    int col = (w * 2 + t) * 16 + l15;
    float bs = bdout[col];
#pragma unroll
    for (int r = 0; r < 4; ++r) {
      int row = lg * 4 + r;
      epi[row * EPIP + col] = acc2[t][r] + bs;
    }
  }
  __syncthreads();

#pragma unroll
  for (int rr = 0; rr < 4; ++rr) {
    int row = w * 4 + rr;
    int node = node0 + row;
    float x0 = epi[row * EPIP + lane] + hV1[node * 128 + lane];
    float x1 = epi[row * EPIP + 64 + lane] + hV1[node * 128 + 64 + lane];
    float s = x0 + x1, q = x0 * x0 + x1 * x1;
#pragma unroll
    for (int off = 1; off < 64; off <<= 1) {
      s += __shfl_xor(s, off);
      q += __shfl_xor(q, off);
    }
    float mean = s * (1.0f / 128.0f);
    float var = q * (1.0f / 128.0f) - mean * mean;
    float rstd = rsqrtf(var + 1e-5f);
    float mv = maskV[node];
    float y0 = mv * ((x0 - mean) * rstd * g2[lane] + be2[lane]);
    float y1 = mv * ((x1 - mean) * rstd * g2[64 + lane] + be2[64 + lane]);
    outV[node * 128 + lane] = y0;
    outV[node * 128 + 64 + lane] = y1;
    hV2b[node * 128 + lane] = f2b(y0);
    hV2b[node * 128 + 64 + lane] = f2b(y1);
  }
}

// ---------------- K3: edge MLP + residual + LN3 (2 nodes/block) ----------------
// LDS: xt [96][264] @0 (50688) | midA overlays xt @0 (26112) | midB @26112 (26112) |
//      nbr @52224 (384) = 52608 B; partials overlay dead midA @0 post-L3
__global__ __launch_bounds__(256, 3) void k_edge(
    const float* __restrict__ hE, const int* __restrict__ eidx,
    const float* __restrict__ bias2, const float* __restrict__ bias3,
    const float* __restrict__ g3, const float* __restrict__ be3,
    const uint16_t* __restrict__ hV2b, const float* __restrict__ C2,
    const uint16_t* __restrict__ W1t, const uint16_t* __restrict__ W2t,
    const uint16_t* __restrict__ W3t,
    float* __restrict__ outE) {
  __shared__ __align__(16) unsigned char lds[52608];
  uint16_t* xt = (uint16_t*)lds;
  uint16_t* midA = (uint16_t*)lds;
  uint16_t* midB = (uint16_t*)(lds + 26112);
  int* nbr = (int*)(lds + 52224);
  float* part_s = (float*)lds;            // [96][4] overlays dead midA
  float* part_q = (float*)(lds + 1536);   // [96][4]
  float* mstd = (float*)(lds + 3072);     // [96][2] (mean, rstd)

  const int tid = threadIdx.x;
  const int lane = tid & 63;
  const int w = tid >> 6;
  const int l15 = lane & 15;
  const int lg = lane >> 4;
  const int nd0 = blockIdx.x * 2;
  const int base = blockIdx.x * 96;

  bf16x8 w1f[16];
  PRELOAD_W384(W1t, w1f);

  if (tid < 96) {
    int e = base + tid;
    nbr[tid] = ((e >= 98304) ? 2048 : 0) + eidx[e];
  }
  __syncthreads();

  BUILD_XT96(hV2b);
  __syncthreads();

  f32x4 acc1[6][2];
  ACC_INIT6(acc1, C2);
  LAYER256R6(w1f, acc1);
  bf16x8 w2f[8];
  PRELOAD_W128(W2t, w2f);
  __syncthreads();               // all xt reads done; midA may overlay
  GSTORE06(acc1, midA);
  __syncthreads();

  f32x4 acc2[6][2] = {};
  LAYER128R6(w2f, midA, acc2);
  bf16x8 w3f[8];
  PRELOAD_W128(W3t, w3f);
  GSTORE6(acc2, bias2, midB);
  __syncthreads();               // midA reads done (partials overlay safe)

  f32x4 acc3[6][2] = {};
  LAYER128R6(w3f, midB, acc3);

  const float bA = bias3[w * 32 + l15];
  const float bB = bias3[w * 32 + 16 + l15];

  // x = acc3 + bias + hE residual, cached in VGPRs for both LN passes
  float xs0[6][4], xs1[6][4];
#pragma unroll
  for (int m = 0; m < 6; ++m)
#pragma unroll
    for (int r = 0; r < 4; ++r) {
      int row = m * 16 + lg * 4 + r;
      size_t e = (size_t)base + row;
      xs0[m][r] = acc3[m][0][r] + bA + hE[e * 128 + w * 32 + l15];
      xs1[m][r] = acc3[m][1][r] + bB + hE[e * 128 + w * 32 + 16 + l15];
      float s = xs0[m][r] + xs1[m][r];
      float q = xs0[m][r] * xs0[m][r] + xs1[m][r] * xs1[m][r];
      s += __shfl_xor(s, 1); q += __shfl_xor(q, 1);
      s += __shfl_xor(s, 2); q += __shfl_xor(q, 2);
      s += __shfl_xor(s, 4); q += __shfl_xor(q, 4);
      s += __shfl_xor(s, 8); q += __shfl_xor(q, 8);
      if (l15 == 0) { part_s[row * 4 + w] = s; part_q[row * 4 + w] = q; }
    }
  __syncthreads();

  if (tid < 96) {
    float s = part_s[tid * 4] + part_s[tid * 4 + 1] + part_s[tid * 4 + 2] + part_s[tid * 4 + 3];
    float q = part_q[tid * 4] + part_q[tid * 4 + 1] + part_q[tid * 4 + 2] + part_q[tid * 4 + 3];
    float mean = s * (1.0f / 128.0f);
    float var = q * (1.0f / 128.0f) - mean * mean;
    mstd[tid * 2] = mean;
    mstd[tid * 2 + 1] = rsqrtf(var + 1e-5f);
  }
  __syncthreads();

  const float gA = g3[w * 32 + l15], beA = be3[w * 32 + l15];
  const float gB = g3[w * 32 + 16 + l15], beB = be3[w * 32 + 16 + l15];
#pragma unroll
  for (int m = 0; m < 6; ++m)
#pragma unroll
    for (int r = 0; r < 4; ++r) {
      int row = m * 16 + lg * 4 + r;
      size_t e = (size_t)base + row;
      float mean = mstd[row * 2];
      float rstd = mstd[row * 2 + 1];
      outE[e * 128 + w * 32 + l15] = (xs0[m][r] - mean) * rstd * gA + beA;
      outE[e * 128 + w * 32 + 16 + l15] = (xs1[m][r] - mean) * rstd * gB + beB;
    }
}

extern "C" void kernel_launch(void* const* d_in, const int* in_sizes, int n_in,
                              void* d_out, int out_size, void* d_ws, size_t ws_size,
                              hipStream_t stream) {
  const float* hV = (const float*)d_in[0];
  const float* hE = (const float*)d_in[1];
  const int* eidx = (const int*)d_in[2];
  const float* maskV = (const float*)d_in[3];
  const float* maskA = (const float*)d_in[4];
  const float* W1 = (const float*)d_in[5];   const float* b1 = (const float*)d_in[6];
  const float* W2 = (const float*)d_in[7];   const float* b2 = (const float*)d_in[8];
  const float* W3 = (const float*)d_in[9];   const float* b3 = (const float*)d_in[10];
  const float* WdIn = (const float*)d_in[11];  const float* bdin = (const float*)d_in[12];
  const float* WdOut = (const float*)d_in[13]; const float* bdout = (const float*)d_in[14];
  const float* W11 = (const float*)d_in[15]; const float* b11 = (const float*)d_in[16];
  const float* W12 = (const float*)d_in[17]; const float* b12 = (const float*)d_in[18];
  const float* W13 = (const float*)d_in[19]; const float* b13 = (const float*)d_in[20];
  const float* n1g = (const float*)d_in[21]; const float* n1b = (const float*)d_in[22];
  const float* n2g = (const float*)d_in[23]; const float* n2b = (const float*)d_in[24];
  const float* n3g = (const float*)d_in[25]; const float* n3b = (const float*)d_in[26];

  char* ws = (char*)d_ws;
  uint16_t* hVb    = (uint16_t*)(ws + 0);
  uint16_t* W1t    = (uint16_t*)(ws + 1048576);
  uint16_t* W2t    = (uint16_t*)(ws + 1146880);
  uint16_t* W3t    = (uint16_t*)(ws + 1179648);
  uint16_t* WdInT  = (uint16_t*)(ws + 1212416);
  uint16_t* WdOutT = (uint16_t*)(ws + 1343488);
  uint16_t* W11t   = (uint16_t*)(ws + 1474560);
  uint16_t* W12t   = (uint16_t*)(ws + 1572864);
  uint16_t* W13t   = (uint16_t*)(ws + 1605632);
  float*    hV1    = (float*)(ws + 1638400);
  uint16_t* hV1b   = (uint16_t*)(ws + 3735552);
  uint16_t* hV2b   = (uint16_t*)(ws + 4784128);
  float*    C1     = (float*)(ws + 5832704);
  float*    C2     = (float*)(ws + 7929856);

  float* outV = (float*)d_out;
  float* outE = (float*)d_out + 524288;

  k_prep<<<3200, 256, 0, stream>>>(hV, W1, W2, W3, WdIn, WdOut, W11, W12, W13,
                                   hVb, W1t, W2t, W3t, WdInT, WdOutT, W11t, W12t, W13t);
  k_vec<<<64, 256, 0, stream>>>(hVb, W1t, b1, C1);
  k_node<<<2048, 256, 0, stream>>>(hV, hE, eidx, maskA, b2, b3, n1g, n1b,
                                   hVb, C1, W1t, W2t, W3t, hV1, hV1b);
  k_ffn<<<256, 256, 0, stream>>>(hV1, hV1b, maskV, bdin, bdout, n2g, n2b,
                                 WdInT, WdOutT, outV, hV2b);
  k_vec<<<64, 256, 0, stream>>>(hV2b, W11t, b11, C2);
  k_edge<<<2048, 256, 0, stream>>>(hE, eidx, b12, b13, n3g, n3b,
                                   hV2b, C2, W11t, W12t, W13t, outE);
}